// Round 4
// baseline (7604.657 us; speedup 1.0000x reference)
//
#include <hip/hip_runtime.h>

// GRU encoder: B=64, T=256, U=1024, VOCAB=10000. f32 tensors on device.
// Persistent cooperative kernel: 256 blocks x 256 threads (1 block/CU).
// block = (ri, cj): ri = batch rowgroup (4 x 16 rows), cj = unit colgroup
// (64 x 16 cols). Waves K-split (4 x 256). W_rec bf16 MFMA fragments live in
// VGPRs for the whole sequence; h carry is exact f32 in registers; the bf16
// exchange buffer is double-buffered with per-rowgroup release/acquire flag
// sync (rows don't interact across rowgroups, so only 64 blocks per barrier).
#define BB 64
#define TT 256
#define UU 1024
#define NG 3072

typedef __attribute__((ext_vector_type(8))) __bf16 bf16x8;
typedef __attribute__((ext_vector_type(4))) float f32x4;

__device__ __forceinline__ unsigned short f2bf(float f) {
    union { unsigned int i; float f; } c; c.f = f;
    unsigned int r = c.i + 0x7FFFu + ((c.i >> 16) & 1u);  // RNE
    return (unsigned short)(r >> 16);
}

union U16x8 { unsigned short us[8]; uint4 u4; };

// ---------------------------------------------------------------------------
// Pack W_rec (f32) into bf16 MFMA B-fragment order (validated in round 3).
// wpack[((cj*4+kc)*24 + g*8 + s)*64 + lane] = 8 bf16:
//   B[k = kc*256 + s*32 + (lane>>4)*8 + j][n = (cj<<4)+(lane&15)], j=0..7
// ---------------------------------------------------------------------------
__global__ __launch_bounds__(256) void pack_kernel(
    const float* __restrict__ w_rec,    // (1024, 3072) f32
    uint4* __restrict__ wpack)
{
    const int tid  = threadIdx.x;
    const int kc   = tid >> 6;
    const int lane = tid & 63;
    const int l16  = lane & 15;
    const int quad = lane >> 4;
    const int cj   = blockIdx.x;
    const int colb = (cj << 4) + l16;

    #pragma unroll
    for (int g = 0; g < 3; ++g) {
        #pragma unroll
        for (int s = 0; s < 8; ++s) {
            const int kb = (kc << 8) + (s << 5) + (quad << 3);
            U16x8 c;
            #pragma unroll
            for (int j = 0; j < 8; ++j)
                c.us[j] = f2bf(w_rec[(size_t)(kb + j) * NG + g * UU + colb]);
            wpack[(size_t)(((cj * 4 + kc) * 24) + g * 8 + s) * 64 + lane] = c.u4;
        }
    }
}

// Seed bf16 exchange buffer parity 0 from f32 hidden.
__global__ __launch_bounds__(256) void seed_kernel(
    const float* __restrict__ hidden,
    unsigned short* __restrict__ hbuf)
{
    const int i = blockIdx.x * 256 + threadIdx.x;   // 65536
    hbuf[i] = f2bf(hidden[i]);
}

// ---------------------------------------------------------------------------
// Persistent GRU kernel: all 256 steps, flag-synced per rowgroup.
// ---------------------------------------------------------------------------
__global__ __launch_bounds__(256) void gru_persist(
    const int* __restrict__ x,              // (64, 256) int32
    const float* __restrict__ hidden,       // (64, 1024) f32
    const float* __restrict__ w_in,         // (10000, 3072) f32
    const float* __restrict__ b_in,         // (3072,) f32
    const float* __restrict__ b_rec,        // (3072,) f32
    const uint4* __restrict__ wpack,        // packed W_rec bf16 frags
    float* __restrict__ out,                // (64,256,1024) + (64,1024) f32
    unsigned short* __restrict__ hbuf,      // ws: 2 x 64 x 1024 bf16
    unsigned int* __restrict__ flags)       // ws: 256 x 4 uint, zeroed
{
    const int tid  = threadIdx.x;
    const int wave = tid >> 6;        // K-chunk 0..3
    const int lane = tid & 63;
    const int l16  = lane & 15;
    const int quad = lane >> 4;

    const int ri   = blockIdx.x >> 6;  // 0..3
    const int cj   = blockIdx.x & 63;  // 0..63
    const int row0 = ri << 4;
    const int col0 = cj << 4;

    __align__(16) __shared__ float red[4][3][64][4];   // 12 KB

    // ---- B-fragments resident in VGPRs for the whole sequence ----
    uint4 wf[3][8];
    {
        const uint4* wp = wpack + (size_t)((cj * 4 + wave) * 24) * 64 + lane;
        #pragma unroll
        for (int g = 0; g < 3; ++g)
            #pragma unroll
            for (int s = 0; s < 8; ++s)
                wf[g][s] = wp[(g * 8 + s) * 64];
    }

    // ---- per-thread gate element ----
    const int em = tid >> 4;
    const int en = tid & 15;
    const int gb = row0 + em;
    const int gu = col0 + en;
    // C/D layout (col=lane&15, row=(lane>>4)*4+reg) -> source lane/reg
    const int rl = ((em >> 2) << 4) | en;
    const int rr = em & 3;

    const float bz  = b_in[gu]          + b_rec[gu];
    const float br  = b_in[UU + gu]     + b_rec[UU + gu];
    const float bih = b_in[2 * UU + gu];
    const float brh = b_rec[2 * UU + gu];

    float hreg = hidden[gb * UU + gu];      // exact f32 carry

    const unsigned short* aband =
        hbuf + (size_t)(row0 + l16) * UU + (wave << 8) + (quad << 3);

    for (int t = 0; t < TT; ++t) {
        // ---- embedding gather: h-independent, issue before the spin ----
        const int xv = x[gb * TT + t];
        const size_t wrow = (size_t)xv * NG;
        const float wz = w_in[wrow + gu];
        const float wr = w_in[wrow + UU + gu];
        const float wh = w_in[wrow + 2 * UU + gu];

        if (t > 0) {
            if (tid == 0) {
                const unsigned int* f = flags + (t - 1) * 4 + ri;
                while (__hip_atomic_load(f, __ATOMIC_RELAXED,
                                         __HIP_MEMORY_SCOPE_AGENT) < 64u) {}
            }
            __syncthreads();
            __threadfence();   // agent acquire: drop stale h lines from L1/L2
        }

        // ---- A from bf16 exchange buffer, parity t&1 ----
        const unsigned short* arow = aband + (size_t)(t & 1) * (BB * UU);
        f32x4 acc0 = {0.f, 0.f, 0.f, 0.f};
        f32x4 acc1 = {0.f, 0.f, 0.f, 0.f};
        f32x4 acc2 = {0.f, 0.f, 0.f, 0.f};
        #pragma unroll
        for (int s = 0; s < 8; ++s) {
            const uint4 av = *(const uint4*)(arow + (s << 5));
            const bf16x8 a = __builtin_bit_cast(bf16x8, av);
            acc0 = __builtin_amdgcn_mfma_f32_16x16x32_bf16(
                a, __builtin_bit_cast(bf16x8, wf[0][s]), acc0, 0, 0, 0);
            acc1 = __builtin_amdgcn_mfma_f32_16x16x32_bf16(
                a, __builtin_bit_cast(bf16x8, wf[1][s]), acc1, 0, 0, 0);
            acc2 = __builtin_amdgcn_mfma_f32_16x16x32_bf16(
                a, __builtin_bit_cast(bf16x8, wf[2][s]), acc2, 0, 0, 0);
        }

        // ---- cross-wave K reduction ----
        *(f32x4*)&red[wave][0][lane][0] = acc0;
        *(f32x4*)&red[wave][1][lane][0] = acc1;
        *(f32x4*)&red[wave][2][lane][0] = acc2;
        __syncthreads();

        const float rz = red[0][0][rl][rr] + red[1][0][rl][rr]
                       + red[2][0][rl][rr] + red[3][0][rl][rr];
        const float rrv = red[0][1][rl][rr] + red[1][1][rl][rr]
                        + red[2][1][rl][rr] + red[3][1][rl][rr];
        const float rh = red[0][2][rl][rr] + red[1][2][rl][rr]
                       + red[2][2][rl][rr] + red[3][2][rl][rr];

        // ---- gates ----
        const float z  = 1.f / (1.f + expf(-(wz + rz + bz)));
        const float r  = 1.f / (1.f + expf(-(wr + rrv + br)));
        const float hh = tanhf(wh + bih + r * (rh + brh));
        const float hn = z * hreg + (1.f - z) * hh;
        hreg = hn;

        out[((size_t)gb * TT + t) * UU + gu] = hn;
        hbuf[(size_t)((t + 1) & 1) * (BB * UU) + gb * UU + gu] = f2bf(hn);

        // all stores drained (syncthreads emits vmcnt(0)), then release-add
        __syncthreads();
        if (tid == 0)
            __hip_atomic_fetch_add(flags + t * 4 + ri, 1u,
                                   __ATOMIC_RELEASE, __HIP_MEMORY_SCOPE_AGENT);
    }

    out[(size_t)BB * TT * UU + (size_t)gb * UU + gu] = hreg;
}

extern "C" void kernel_launch(void* const* d_in, const int* in_sizes, int n_in,
                              void* d_out, int out_size, void* d_ws, size_t ws_size,
                              hipStream_t stream) {
    const int* x        = (const int*)d_in[0];
    const float* hidden = (const float*)d_in[1];
    const float* w_in   = (const float*)d_in[2];
    const float* w_rec  = (const float*)d_in[3];
    const float* b_in   = (const float*)d_in[4];
    const float* b_rec  = (const float*)d_in[5];
    float* out          = (float*)d_out;

    unsigned char* ws = (unsigned char*)d_ws;
    uint4* wpack         = (uint4*)ws;                        // 6 MB
    unsigned short* hbuf = (unsigned short*)(ws + 6291456);   // 256 KB
    unsigned int* flags  = (unsigned int*)(ws + 6291456 + 262144);  // 4 KB

    hipMemsetAsync(flags, 0, TT * 4 * sizeof(unsigned int), stream);
    pack_kernel<<<64, 256, 0, stream>>>(w_rec, wpack);
    seed_kernel<<<256, 256, 0, stream>>>(hidden, hbuf);

    void* args[] = { (void*)&x, (void*)&hidden, (void*)&w_in, (void*)&b_in,
                     (void*)&b_rec, (void*)&wpack, (void*)&out,
                     (void*)&hbuf, (void*)&flags };
    hipLaunchCooperativeKernel((void*)gru_persist, dim3(256), dim3(256),
                               args, 0, stream);
}

// Round 5
// 6220.996 us; speedup vs baseline: 1.2224x; 1.2224x over previous
//
#include <hip/hip_runtime.h>

// GRU encoder: B=64, T=256, U=1024, VOCAB=10000. f32 tensors on device.
// Persistent cooperative kernel: 256 blocks x 256 threads (1 block/CU).
// block -> (ri, cj) with XCD-aware mapping: ri = (blockIdx&7)>>1 puts each
// batch rowgroup's 64 blocks on one XCD pair (blockIdx%8 round-robin
// heuristic; perf-only). Sync: per-block epoch flag slots (64 B apart,
// uncontended release fetch_add) + parallel 64-lane relaxed poll +
// __threadfence acquire — same primitive semantics round 4 validated,
// minus the contended single-counter serialization that cost 29 us/step.
#define BB 64
#define TT 256
#define UU 1024
#define NG 3072

typedef __attribute__((ext_vector_type(8))) __bf16 bf16x8;
typedef __attribute__((ext_vector_type(4))) float f32x4;

__device__ __forceinline__ unsigned short f2bf(float f) {
    union { unsigned int i; float f; } c; c.f = f;
    unsigned int r = c.i + 0x7FFFu + ((c.i >> 16) & 1u);  // RNE
    return (unsigned short)(r >> 16);
}

union U16x8 { unsigned short us[8]; uint4 u4; };

// ---------------------------------------------------------------------------
// Pack W_rec (f32) into bf16 MFMA B-fragment order (validated round 3/4).
// wpack[((cj*4+kc)*24 + g*8 + s)*64 + lane] = 8 bf16:
//   B[k = kc*256 + s*32 + (lane>>4)*8 + j][n = (cj<<4)+(lane&15)], j=0..7
// ---------------------------------------------------------------------------
__global__ __launch_bounds__(256) void pack_kernel(
    const float* __restrict__ w_rec,    // (1024, 3072) f32
    uint4* __restrict__ wpack)
{
    const int tid  = threadIdx.x;
    const int kc   = tid >> 6;
    const int lane = tid & 63;
    const int l16  = lane & 15;
    const int quad = lane >> 4;
    const int cj   = blockIdx.x;
    const int colb = (cj << 4) + l16;

    #pragma unroll
    for (int g = 0; g < 3; ++g) {
        #pragma unroll
        for (int s = 0; s < 8; ++s) {
            const int kb = (kc << 8) + (s << 5) + (quad << 3);
            U16x8 c;
            #pragma unroll
            for (int j = 0; j < 8; ++j)
                c.us[j] = f2bf(w_rec[(size_t)(kb + j) * NG + g * UU + colb]);
            wpack[(size_t)(((cj * 4 + kc) * 24) + g * 8 + s) * 64 + lane] = c.u4;
        }
    }
}

// Seed bf16 exchange buffer parity 0 from f32 hidden.
__global__ __launch_bounds__(256) void seed_kernel(
    const float* __restrict__ hidden,
    unsigned short* __restrict__ hbuf)
{
    const int i = blockIdx.x * 256 + threadIdx.x;   // 65536
    hbuf[i] = f2bf(hidden[i]);
}

// ---------------------------------------------------------------------------
// Persistent GRU kernel: all 256 steps, per-rowgroup flag sync.
// flags: 4 rowgroups x 64 slots x 16 uints (64 B spacing), zeroed on entry.
// Slot value after a block finishes step t is t+1 (epoch; monotone).
// ---------------------------------------------------------------------------
__global__ __launch_bounds__(256, 1) void gru_persist(
    const int* __restrict__ x,              // (64, 256) int32
    const float* __restrict__ hidden,       // (64, 1024) f32
    const float* __restrict__ w_in,         // (10000, 3072) f32
    const float* __restrict__ b_in,         // (3072,) f32
    const float* __restrict__ b_rec,        // (3072,) f32
    const uint4* __restrict__ wpack,        // packed W_rec bf16 frags
    float* __restrict__ out,                // (64,256,1024) + (64,1024) f32
    unsigned short* __restrict__ hbuf,      // ws: 2 x 64 x 1024 bf16
    unsigned int* __restrict__ flags)       // ws: 4 x 64 x 16 uint, zeroed
{
    const int tid  = threadIdx.x;
    const int wave = tid >> 6;        // K-chunk 0..3
    const int lane = tid & 63;
    const int l16  = lane & 15;
    const int quad = lane >> 4;

    // XCD-aware block -> (ri, cj): rowgroup ri on XCD pair {2ri, 2ri+1}
    const int bid = blockIdx.x;
    const int ri  = (bid & 7) >> 1;                 // 0..3
    const int cj  = ((bid & 1) << 5) | (bid >> 3);  // 0..63
    const int row0 = ri << 4;
    const int col0 = cj << 4;

    __align__(16) __shared__ float red[4][3][64][4];   // 12 KB

    // ---- B-fragments resident in VGPRs (512-VGPR budget via bounds(256,1)) ----
    uint4 wf[3][8];
    {
        const uint4* wp = wpack + (size_t)((cj * 4 + wave) * 24) * 64 + lane;
        #pragma unroll
        for (int g = 0; g < 3; ++g)
            #pragma unroll
            for (int s = 0; s < 8; ++s)
                wf[g][s] = wp[(g * 8 + s) * 64];
    }

    // ---- per-thread gate element ----
    const int em = tid >> 4;
    const int en = tid & 15;
    const int gb = row0 + em;
    const int gu = col0 + en;
    // C/D layout (col=lane&15, row=(lane>>4)*4+reg) -> source lane/reg
    const int rl = ((em >> 2) << 4) | en;
    const int rr = em & 3;

    const float bz  = b_in[gu]          + b_rec[gu];
    const float br  = b_in[UU + gu]     + b_rec[UU + gu];
    const float bih = b_in[2 * UU + gu];
    const float brh = b_rec[2 * UU + gu];

    float hreg = hidden[gb * UU + gu];      // exact f32 carry

    const unsigned short* aband =
        hbuf + (size_t)(row0 + l16) * UU + (wave << 8) + (quad << 3);
    unsigned int* myslot = flags + (size_t)(ri * 64 + cj) * 16;
    const unsigned int* pollslot = flags + (size_t)(ri * 64 + lane) * 16;

    for (int t = 0; t < TT; ++t) {
        // ---- h-independent gathers issued before the wait ----
        const int xv = x[gb * TT + t];
        const size_t wrow = (size_t)xv * NG;
        const float wz = w_in[wrow + gu];
        const float wr = w_in[wrow + UU + gu];
        const float wh = w_in[wrow + 2 * UU + gu];

        if (t > 0) {
            if (wave == 0) {
                // 64 lanes poll 64 uncontended slots in parallel
                for (;;) {
                    unsigned int v = __hip_atomic_load(
                        pollslot, __ATOMIC_RELAXED, __HIP_MEMORY_SCOPE_AGENT);
                    if (__all((int)(v >= (unsigned int)t))) break;
                }
            }
            __syncthreads();
            __threadfence();   // agent acquire: drop stale h lines
        }

        // ---- A from bf16 exchange buffer, parity t&1 ----
        const unsigned short* arow = aband + (size_t)(t & 1) * (BB * UU);
        f32x4 acc0 = {0.f, 0.f, 0.f, 0.f};
        f32x4 acc1 = {0.f, 0.f, 0.f, 0.f};
        f32x4 acc2 = {0.f, 0.f, 0.f, 0.f};
        #pragma unroll
        for (int s = 0; s < 8; ++s) {
            const uint4 av = *(const uint4*)(arow + (s << 5));
            const bf16x8 a = __builtin_bit_cast(bf16x8, av);
            acc0 = __builtin_amdgcn_mfma_f32_16x16x32_bf16(
                a, __builtin_bit_cast(bf16x8, wf[0][s]), acc0, 0, 0, 0);
            acc1 = __builtin_amdgcn_mfma_f32_16x16x32_bf16(
                a, __builtin_bit_cast(bf16x8, wf[1][s]), acc1, 0, 0, 0);
            acc2 = __builtin_amdgcn_mfma_f32_16x16x32_bf16(
                a, __builtin_bit_cast(bf16x8, wf[2][s]), acc2, 0, 0, 0);
        }

        // ---- cross-wave K reduction ----
        *(f32x4*)&red[wave][0][lane][0] = acc0;
        *(f32x4*)&red[wave][1][lane][0] = acc1;
        *(f32x4*)&red[wave][2][lane][0] = acc2;
        __syncthreads();

        const float rz = red[0][0][rl][rr] + red[1][0][rl][rr]
                       + red[2][0][rl][rr] + red[3][0][rl][rr];
        const float rrv = red[0][1][rl][rr] + red[1][1][rl][rr]
                        + red[2][1][rl][rr] + red[3][1][rl][rr];
        const float rh = red[0][2][rl][rr] + red[1][2][rl][rr]
                       + red[2][2][rl][rr] + red[3][2][rl][rr];

        // ---- gates ----
        const float z  = 1.f / (1.f + expf(-(wz + rz + bz)));
        const float r  = 1.f / (1.f + expf(-(wr + rrv + br)));
        const float hh = tanhf(wh + bih + r * (rh + brh));
        const float hn = z * hreg + (1.f - z) * hh;
        hreg = hn;

        out[((size_t)gb * TT + t) * UU + gu] = hn;
        hbuf[(size_t)((t + 1) & 1) * (BB * UU) + gb * UU + gu] = f2bf(hn);

        // barrier drains every wave's stores (vmcnt(0) before s_barrier),
        // then one uncontended release-RMW publishes epoch t+1
        __syncthreads();
        if (tid == 0)
            __hip_atomic_fetch_add(myslot, 1u,
                                   __ATOMIC_RELEASE, __HIP_MEMORY_SCOPE_AGENT);
    }

    out[(size_t)BB * TT * UU + (size_t)gb * UU + gu] = hreg;
}

extern "C" void kernel_launch(void* const* d_in, const int* in_sizes, int n_in,
                              void* d_out, int out_size, void* d_ws, size_t ws_size,
                              hipStream_t stream) {
    const int* x        = (const int*)d_in[0];
    const float* hidden = (const float*)d_in[1];
    const float* w_in   = (const float*)d_in[2];
    const float* w_rec  = (const float*)d_in[3];
    const float* b_in   = (const float*)d_in[4];
    const float* b_rec  = (const float*)d_in[5];
    float* out          = (float*)d_out;

    unsigned char* ws = (unsigned char*)d_ws;
    uint4* wpack         = (uint4*)ws;                        // 6 MB
    unsigned short* hbuf = (unsigned short*)(ws + 6291456);   // 256 KB
    unsigned int* flags  = (unsigned int*)(ws + 6291456 + 262144);  // 16 KB

    hipMemsetAsync(flags, 0, 4 * 64 * 16 * sizeof(unsigned int), stream);
    pack_kernel<<<64, 256, 0, stream>>>(w_rec, wpack);
    seed_kernel<<<256, 256, 0, stream>>>(hidden, hbuf);

    void* args[] = { (void*)&x, (void*)&hidden, (void*)&w_in, (void*)&b_in,
                     (void*)&b_rec, (void*)&wpack, (void*)&out,
                     (void*)&hbuf, (void*)&flags };
    hipLaunchCooperativeKernel((void*)gru_persist, dim3(256), dim3(256),
                               args, 0, stream);
}